// Round 4
// baseline (113.113 us; speedup 1.0000x reference)
//
#include <hip/hip_runtime.h>

// out = -sum_i[ y*log_sigmoid(x) + (1-y)*log_sigmoid(-x) ] / ((1+neg)*pos)
// per-element with z = (label ? x : -x):
//   term = min(z,0) - log1p(exp(-|z|)),  and |z| == |x|
//
// Single kernel: 2048 blocks grid-stride float4/int4 -> per-block partials in
// d_ws (agent-scope atomic stores), acq-rel counter; the LAST block re-reduces
// the partials in double and writes the final scalar. No separate finalize
// launch. Counter zeroed each call via 4-byte hipMemsetAsync (capture-legal).

#define NBLOCKS 2048
#define TPB 256

__device__ __forceinline__ void bce_elem(float xv, int lv, float& lsum, int& pcnt)
{
    int p = (lv != 0) ? 1 : 0;
    pcnt += p;
    float ax = fabsf(xv);
    float t  = __expf(-ax);            // in (0,1], no overflow
    float c  = __logf(1.0f + t);       // log1p(exp(-|x|)) >= 0
    float z  = p ? xv : -xv;
    lsum += fminf(z, 0.0f) - c;
}

__global__ __launch_bounds__(TPB, 8) void bce_fused_kernel(
    const float* __restrict__ x,
    const int* __restrict__ lab,
    float* __restrict__ psum,            // [NBLOCKS] partial loss sums
    int*   __restrict__ pcount,          // [NBLOCKS] partial positive counts
    unsigned int* __restrict__ counter,  // blocks-done counter (zeroed per call)
    float* __restrict__ out,
    int n)
{
    const int n4 = n >> 2;
    const float4* __restrict__ x4 = reinterpret_cast<const float4*>(x);
    const int4*   __restrict__ l4 = reinterpret_cast<const int4*>(lab);

    float lsum = 0.0f;
    int pcnt = 0;

    const int tid    = blockIdx.x * TPB + threadIdx.x;
    const int stride = gridDim.x * TPB;

    int i = tid;
    // 4x unrolled: 8 independent loads in flight before any dependent use
    for (; i + 3 * stride < n4; i += 4 * stride) {
        float4 a0 = x4[i];
        float4 a1 = x4[i + stride];
        float4 a2 = x4[i + 2 * stride];
        float4 a3 = x4[i + 3 * stride];
        int4   b0 = l4[i];
        int4   b1 = l4[i + stride];
        int4   b2 = l4[i + 2 * stride];
        int4   b3 = l4[i + 3 * stride];

        bce_elem(a0.x, b0.x, lsum, pcnt); bce_elem(a0.y, b0.y, lsum, pcnt);
        bce_elem(a0.z, b0.z, lsum, pcnt); bce_elem(a0.w, b0.w, lsum, pcnt);
        bce_elem(a1.x, b1.x, lsum, pcnt); bce_elem(a1.y, b1.y, lsum, pcnt);
        bce_elem(a1.z, b1.z, lsum, pcnt); bce_elem(a1.w, b1.w, lsum, pcnt);
        bce_elem(a2.x, b2.x, lsum, pcnt); bce_elem(a2.y, b2.y, lsum, pcnt);
        bce_elem(a2.z, b2.z, lsum, pcnt); bce_elem(a2.w, b2.w, lsum, pcnt);
        bce_elem(a3.x, b3.x, lsum, pcnt); bce_elem(a3.y, b3.y, lsum, pcnt);
        bce_elem(a3.z, b3.z, lsum, pcnt); bce_elem(a3.w, b3.w, lsum, pcnt);
    }
    for (; i < n4; i += stride) {
        float4 a = x4[i];
        int4   b = l4[i];
        bce_elem(a.x, b.x, lsum, pcnt); bce_elem(a.y, b.y, lsum, pcnt);
        bce_elem(a.z, b.z, lsum, pcnt); bce_elem(a.w, b.w, lsum, pcnt);
    }
    if (tid == 0) {  // scalar tail (n not multiple of 4)
        for (int k = n4 << 2; k < n; ++k)
            bce_elem(x[k], lab[k], lsum, pcnt);
    }

    // wave (64-lane) reduction
#pragma unroll
    for (int off = 32; off > 0; off >>= 1) {
        lsum += __shfl_down(lsum, off);
        pcnt += __shfl_down(pcnt, off);
    }

    // cross-wave reduction via LDS (4 waves)
    __shared__ float wsum[4];
    __shared__ int   wcnt[4];
    __shared__ int   isLast;
    int wave = threadIdx.x >> 6;
    int lane = threadIdx.x & 63;
    if (lane == 0) { wsum[wave] = lsum; wcnt[wave] = pcnt; }
    __syncthreads();

    if (threadIdx.x == 0) {
        float bs = wsum[0] + wsum[1] + wsum[2] + wsum[3];
        int   bc = wcnt[0] + wcnt[1] + wcnt[2] + wcnt[3];
        // agent-scope atomic stores: visible past this XCD's L2
        __hip_atomic_store(&psum[blockIdx.x], bs,
                           __ATOMIC_RELAXED, __HIP_MEMORY_SCOPE_AGENT);
        __hip_atomic_store(&pcount[blockIdx.x], bc,
                           __ATOMIC_RELAXED, __HIP_MEMORY_SCOPE_AGENT);
        // acq-rel RMW: releases the stores above, acquires all prior blocks'
        unsigned int old = __hip_atomic_fetch_add(counter, 1u,
                           __ATOMIC_ACQ_REL, __HIP_MEMORY_SCOPE_AGENT);
        isLast = (old == (unsigned int)(gridDim.x - 1)) ? 1 : 0;
    }
    __syncthreads();

    if (isLast) {
        // last block: re-reduce all partials (atomic loads bypass stale caches)
        double s = 0.0;
        int    c = 0;
        for (int k = threadIdx.x; k < NBLOCKS; k += TPB) {
            s += (double)__hip_atomic_load(&psum[k],
                         __ATOMIC_RELAXED, __HIP_MEMORY_SCOPE_AGENT);
            c += __hip_atomic_load(&pcount[k],
                         __ATOMIC_RELAXED, __HIP_MEMORY_SCOPE_AGENT);
        }
#pragma unroll
        for (int off = 32; off > 0; off >>= 1) {
            s += __shfl_down(s, off);
            c += __shfl_down(c, off);
        }
        __shared__ double wsd[4];
        __shared__ int    wci[4];
        if (lane == 0) { wsd[wave] = s; wci[wave] = c; }
        __syncthreads();
        if (threadIdx.x == 0) {
            double stot = wsd[0] + wsd[1] + wsd[2] + wsd[3];
            double pos  = (double)(wci[0] + wci[1] + wci[2] + wci[3]);
            double neg  = (double)n - pos;
            double scale = -1.0 / ((1.0 + neg) * pos);
            out[0] = (float)(scale * stot);
        }
    }
}

extern "C" void kernel_launch(void* const* d_in, const int* in_sizes, int n_in,
                              void* d_out, int out_size, void* d_ws, size_t ws_size,
                              hipStream_t stream) {
    const float* x   = (const float*)d_in[0];
    const int*   lab = (const int*)d_in[1];
    int n = in_sizes[0];
    float* out = (float*)d_out;

    // ws layout: [0,8K) float psum | [8K,16K) int pcount | [16K,16K+4) counter
    float* psum         = (float*)d_ws;
    int*   pcnt         = (int*)((char*)d_ws + NBLOCKS * sizeof(float));
    unsigned int* cnt   = (unsigned int*)((char*)d_ws + 2 * NBLOCKS * sizeof(float));

    // counter must start at 0 every call (ws is poisoned 0xAA once, never
    // re-poisoned): 4-byte async memset is graph-capture-legal.
    hipMemsetAsync(cnt, 0, sizeof(unsigned int), stream);

    bce_fused_kernel<<<NBLOCKS, TPB, 0, stream>>>(x, lab, psum, pcnt, cnt, out, n);
}

// Round 5
// 48.688 us; speedup vs baseline: 2.3232x; 2.3232x over previous
//
#include <hip/hip_runtime.h>

// out = -sum_i[ y*log_sigmoid(x) + (1-y)*log_sigmoid(-x) ] / ((1+neg)*pos)
// per-element with z = (label ? x : -x):
//   term = min(z,0) - log1p(exp(-|z|)),  and |z| == |x|
//
// Stage 1: 2048 blocks, each owning a CONTIGUOUS chunk of the input
//          (better DRAM-row / L2-sector locality than grid-stride),
//          float4/int4 loads, 4x unrolled, per-block partials -> d_ws.
//          No global atomics (R2 showed atomic tail cost ~27us), no
//          device-scope fences (R4 showed acq-rel L2 flushes cost 2x).
// Stage 2: one block reduces the 2048 partials in double and finalizes.

#define NBLOCKS 2048
#define TPB 256

__device__ __forceinline__ void bce_elem(float xv, int lv, float& lsum, int& pcnt)
{
    int p = (lv != 0) ? 1 : 0;
    pcnt += p;
    float ax = fabsf(xv);
    float t  = __expf(-ax);            // in (0,1], no overflow
    float c  = __logf(1.0f + t);       // log1p(exp(-|x|)) >= 0
    float z  = p ? xv : -xv;
    lsum += fminf(z, 0.0f) - c;
}

__global__ __launch_bounds__(TPB, 8) void bce_reduce_kernel(
    const float* __restrict__ x,
    const int* __restrict__ lab,
    float* __restrict__ psum,      // [NBLOCKS] per-block loss partials
    int*   __restrict__ pcount,    // [NBLOCKS] per-block positive counts
    int n)
{
    const int n4 = n >> 2;
    const float4* __restrict__ x4 = reinterpret_cast<const float4*>(x);
    const int4*   __restrict__ l4 = reinterpret_cast<const int4*>(lab);

    // balanced contiguous partition of n4 float4-groups across blocks
    const int chunk = n4 / NBLOCKS;
    const int rem   = n4 % NBLOCKS;
    const int b     = blockIdx.x;
    const int start = b * chunk + (b < rem ? b : rem);
    const int cnt   = chunk + (b < rem ? 1 : 0);
    const int end   = start + cnt;

    float lsum = 0.0f;
    int pcnt = 0;

    int i = start + threadIdx.x;
    // 4x unrolled within the contiguous chunk: 8 independent loads in flight
    for (; i + 3 * TPB < end; i += 4 * TPB) {
        float4 a0 = x4[i];
        float4 a1 = x4[i + TPB];
        float4 a2 = x4[i + 2 * TPB];
        float4 a3 = x4[i + 3 * TPB];
        int4   b0 = l4[i];
        int4   b1 = l4[i + TPB];
        int4   b2 = l4[i + 2 * TPB];
        int4   b3 = l4[i + 3 * TPB];

        bce_elem(a0.x, b0.x, lsum, pcnt); bce_elem(a0.y, b0.y, lsum, pcnt);
        bce_elem(a0.z, b0.z, lsum, pcnt); bce_elem(a0.w, b0.w, lsum, pcnt);
        bce_elem(a1.x, b1.x, lsum, pcnt); bce_elem(a1.y, b1.y, lsum, pcnt);
        bce_elem(a1.z, b1.z, lsum, pcnt); bce_elem(a1.w, b1.w, lsum, pcnt);
        bce_elem(a2.x, b2.x, lsum, pcnt); bce_elem(a2.y, b2.y, lsum, pcnt);
        bce_elem(a2.z, b2.z, lsum, pcnt); bce_elem(a2.w, b2.w, lsum, pcnt);
        bce_elem(a3.x, b3.x, lsum, pcnt); bce_elem(a3.y, b3.y, lsum, pcnt);
        bce_elem(a3.z, b3.z, lsum, pcnt); bce_elem(a3.w, b3.w, lsum, pcnt);
    }
    for (; i < end; i += TPB) {
        float4 a = x4[i];
        int4   bb = l4[i];
        bce_elem(a.x, bb.x, lsum, pcnt); bce_elem(a.y, bb.y, lsum, pcnt);
        bce_elem(a.z, bb.z, lsum, pcnt); bce_elem(a.w, bb.w, lsum, pcnt);
    }
    // scalar tail (n not multiple of 4) handled by one thread
    if (b == 0 && threadIdx.x == 0) {
        for (int k = n4 << 2; k < n; ++k)
            bce_elem(x[k], lab[k], lsum, pcnt);
    }

    // wave (64-lane) reduction
#pragma unroll
    for (int off = 32; off > 0; off >>= 1) {
        lsum += __shfl_down(lsum, off);
        pcnt += __shfl_down(pcnt, off);
    }

    // cross-wave reduction via LDS (4 waves)
    __shared__ float wsum[4];
    __shared__ int   wcnt[4];
    int wave = threadIdx.x >> 6;
    int lane = threadIdx.x & 63;
    if (lane == 0) { wsum[wave] = lsum; wcnt[wave] = pcnt; }
    __syncthreads();
    if (threadIdx.x == 0) {
        psum[blockIdx.x]   = wsum[0] + wsum[1] + wsum[2] + wsum[3];
        pcount[blockIdx.x] = wcnt[0] + wcnt[1] + wcnt[2] + wcnt[3];
    }
}

__global__ __launch_bounds__(256) void bce_finalize_kernel(
    const float* __restrict__ psum,
    const int*   __restrict__ pcount,
    float* __restrict__ out, int n, int nparts)
{
    double s = 0.0;
    int    c = 0;
    for (int i = threadIdx.x; i < nparts; i += 256) {
        s += (double)psum[i];
        c += pcount[i];
    }
#pragma unroll
    for (int off = 32; off > 0; off >>= 1) {
        s += __shfl_down(s, off);
        c += __shfl_down(c, off);
    }
    __shared__ double wsd[4];
    __shared__ int    wci[4];
    int wave = threadIdx.x >> 6;
    int lane = threadIdx.x & 63;
    if (lane == 0) { wsd[wave] = s; wci[wave] = c; }
    __syncthreads();
    if (threadIdx.x == 0) {
        double stot = wsd[0] + wsd[1] + wsd[2] + wsd[3];
        double pos  = (double)(wci[0] + wci[1] + wci[2] + wci[3]);
        double neg  = (double)n - pos;
        double scale = -1.0 / ((1.0 + neg) * pos);
        out[0] = (float)(scale * stot);
    }
}

extern "C" void kernel_launch(void* const* d_in, const int* in_sizes, int n_in,
                              void* d_out, int out_size, void* d_ws, size_t ws_size,
                              hipStream_t stream) {
    const float* x   = (const float*)d_in[0];
    const int*   lab = (const int*)d_in[1];
    int n = in_sizes[0];
    float* out = (float*)d_out;

    // ws layout: [0, 8KB) float partial sums, [8KB, 16KB) int partial counts.
    // Every slot is written unconditionally each call -> no memset needed,
    // no state carried across replays.
    float* psum  = (float*)d_ws;
    int*   pcnt  = (int*)((char*)d_ws + NBLOCKS * sizeof(float));

    bce_reduce_kernel<<<NBLOCKS, TPB, 0, stream>>>(x, lab, psum, pcnt, n);
    bce_finalize_kernel<<<1, 256, 0, stream>>>(psum, pcnt, out, n, NBLOCKS);
}